// Round 11
// baseline (381.376 us; speedup 1.0000x reference)
//
#include <hip/hip_runtime.h>
#include <cfloat>

#define N_PTS 8192
#define DTOK 256
#define KNN 16
#define NCHUNK 16
#define CHUNK 512   // N_PTS / NCHUNK

typedef __attribute__((ext_vector_type(8))) short short8;
typedef __attribute__((ext_vector_type(4))) float float4v;

__device__ inline short f2bf(float f) {   // RTNE fp32 -> bf16
  unsigned u = __float_as_uint(f);
  u += 0x7fffu + ((u >> 16) & 1u);
  return (short)(u >> 16);
}
__device__ inline float bf2f(short h) {
  return __uint_as_float(((unsigned)(unsigned short)h) << 16);
}

// ---------------------------------------------------------------------------
// KNN stage 1 (frozen from R10).
// ---------------------------------------------------------------------------
__global__ __launch_bounds__(256) void knn_partial_kernel(
    const float* __restrict__ xyz, uint2* __restrict__ part) {
  __shared__ float4 s4[CHUNK];        // x,y,z,sq : 8 KB
  __shared__ uint2 sbuf[KNN][256];    // FIFO [slot][tid] : 32 KB
  const int t = threadIdx.x;
  const int cbase = blockIdx.y * CHUNK;

  #pragma unroll
  for (int r = 0; r < CHUNK / 256; ++r) {
    int jj = t + 256 * r;
    int j = cbase + jj;
    float x = xyz[3 * j], y = xyz[3 * j + 1], z = xyz[3 * j + 2];
    float sq = __fadd_rn(__fadd_rn(__fmul_rn(x, x), __fmul_rn(y, y)),
                         __fmul_rn(z, z));
    s4[jj] = make_float4(x, y, z, sq);
  }
  __syncthreads();

  const int i = blockIdx.x * 256 + t;
  const float xi = xyz[3 * i], yi = xyz[3 * i + 1], zi = xyz[3 * i + 2];
  const float sqi = __fadd_rn(__fadd_rn(__fmul_rn(xi, xi), __fmul_rn(yi, yi)),
                              __fmul_rn(zi, zi));

  float bd[KNN];
  int bx[KNN];
  #pragma unroll
  for (int s = 0; s < KNN; ++s) { bd[s] = FLT_MAX; bx[s] = 0; }
  int cnt = 0;

  auto drain = [&]() {
    int tt = 0;
    while (__any(tt < cnt)) {
      float d = FLT_MAX;
      int j = 0;
      if (tt < cnt) {
        uint2 e = sbuf[tt][t];
        d = __uint_as_float(e.x);
        j = (int)e.y;
      }
      bool c[KNN];
      #pragma unroll
      for (int s = 0; s < KNN; ++s) c[s] = d < bd[s];
      #pragma unroll
      for (int s = KNN - 1; s >= 1; --s) {
        bd[s] = c[s - 1] ? bd[s - 1] : (c[s] ? d : bd[s]);
        bx[s] = c[s - 1] ? bx[s - 1] : (c[s] ? j : bx[s]);
      }
      bd[0] = c[0] ? d : bd[0];
      bx[0] = c[0] ? j : bx[0];
      ++tt;
    }
    cnt = 0;
  };

  for (int jj = 0; jj < CHUNK; jj += 2) {
    #pragma unroll
    for (int u = 0; u < 2; ++u) {
      float4 p = s4[jj + u];
      float dot = fmaf(zi, p.z, fmaf(yi, p.y, __fmul_rn(xi, p.x)));
      float d = __fadd_rn(__fsub_rn(sqi, __fmul_rn(2.0f, dot)), p.w);
      int j = cbase + jj + u;
      if (j == i) d = __fadd_rn(d, 1e10f);
      if (d < bd[KNN - 1]) {
        sbuf[cnt][t] = make_uint2(__float_as_uint(d), (unsigned)j);
        ++cnt;
      }
    }
    if (__any(cnt >= KNN - 1)) drain();
  }
  drain();

  #pragma unroll
  for (int s = 0; s < KNN; ++s) {
    int slot = blockIdx.y * KNN + s;
    part[(size_t)slot * N_PTS + i] =
        make_uint2(__float_as_uint(bd[s]), (unsigned)bx[s]);
  }
}

// ---------------------------------------------------------------------------
// KNN stage 2 (frozen).
// ---------------------------------------------------------------------------
__global__ __launch_bounds__(256) void knn_merge_kernel(
    const uint2* __restrict__ part, int* __restrict__ nbr) {
  __shared__ uint2 sl[KNN * 256];     // [slot][tid] : 32 KB
  const int t = threadIdx.x;
  const int c = t & 15;               // chunk this lane owns
  const int i = blockIdx.x * 16 + (t >> 4);

  float hd;  int hj;
  {
    uint2 e0 = part[(size_t)(c * KNN) * N_PTS + i];
    hd = __uint_as_float(e0.x);
    hj = (int)e0.y;
    #pragma unroll
    for (int s = 1; s < KNN; ++s)
      sl[s * 256 + t] = part[(size_t)(c * KNN + s) * N_PTS + i];
  }

  int idx = 1;
  int outj = 0;
  #pragma unroll
  for (int r = 0; r < KNN; ++r) {
    float md = hd;  int mc = c;
    #pragma unroll
    for (int m = 1; m < 16; m <<= 1) {
      float od = __shfl_xor(md, m, 16);
      int oc = __shfl_xor(mc, m, 16);
      bool take = (od < md) || (od == md && oc < mc);
      md = take ? od : md;
      mc = take ? oc : mc;
    }
    int jw = __shfl(hj, mc, 16);
    if (c == r) outj = jw;
    if (c == mc) {
      if (idx < KNN) {
        uint2 e = sl[idx * 256 + t];
        hd = __uint_as_float(e.x);
        hj = (int)e.y;
      } else {
        hd = FLT_MAX;  hj = 0;
      }
      ++idx;
    }
  }
  nbr[i * KNN + c] = outj;
}

// ---------------------------------------------------------------------------
// W1 -> Bt (transposed, n-major) bf16 hi/lo (frozen).
// ---------------------------------------------------------------------------
__global__ __launch_bounds__(256) void convert_w_kernel(
    const float* __restrict__ W1, short* __restrict__ bhi,
    short* __restrict__ blo) {
  const int n = blockIdx.x;      // 0..511
  const int k = threadIdx.x;     // 0..255
  const float v = (n < 256) ? W1[k * DTOK + n]
                            : W1[(259 + k) * DTOK + (n - 256)];
  short h = f2bf(v);
  bhi[n * 256 + k] = h;
  blo[n * 256 + k] = f2bf(v - bf2f(h));
}

// ---------------------------------------------------------------------------
// W2 -> Bt2 (transposed, n-major, bf16). Same f2bf as the old in-kernel
// conversion -> B-operand values bit-identical to R10's bfr.
// ---------------------------------------------------------------------------
__global__ __launch_bounds__(256) void convert_w2_kernel(
    const float* __restrict__ W2, short* __restrict__ bt2) {
  const int n = blockIdx.x;      // 0..255
  const int k = threadIdx.x;     // 0..255
  bt2[n * 256 + k] = f2bf(W2[k * DTOK + n]);
}

// ---------------------------------------------------------------------------
// pq GEMM v2 (frozen from R9).
// ---------------------------------------------------------------------------
__global__ __launch_bounds__(256, 2) void pq_gemm_fused_kernel(
    const float* __restrict__ A, const short* __restrict__ Bthi,
    const short* __restrict__ Btlo, const float* __restrict__ xyz,
    const float* __restrict__ W1, const float* __restrict__ b1,
    float* __restrict__ R, float* __restrict__ Q) {
  __shared__ short Ahi[64][32], Alo[64][32];    // 4K + 4K
  __shared__ short Bhi[128][32], Blo[128][32];  // 8K + 8K
  __shared__ float Qs[64][65];                  // 16.6K
  __shared__ float sx[64][3];
  __shared__ float swz[6][64];
  __shared__ float sb1[64];

  const int tid = threadIdx.x;
  const int lane = tid & 63;
  const int wave = tid >> 6;
  const int l15 = lane & 15;
  const int quad = lane >> 4;
  const int mh = wave & 1;
  const int qh = wave >> 1;
  const int m0 = blockIdx.x * 64;
  const int np0 = blockIdx.y * 64;

  if (tid < 64) {
    sx[tid][0] = xyz[(m0 + tid) * 3];
    sx[tid][1] = xyz[(m0 + tid) * 3 + 1];
    sx[tid][2] = xyz[(m0 + tid) * 3 + 2];
  } else if (tid < 128) {
    int n = tid - 64;
    sb1[n] = b1[np0 + n];
    #pragma unroll
    for (int r = 0; r < 3; ++r) {
      swz[r][n] = W1[(256 + r) * DTOK + np0 + n];
      swz[3 + r][n] = W1[(515 + r) * DTOK + np0 + n];
    }
  }

  float4v acc[2][4];
  #pragma unroll
  for (int mf = 0; mf < 2; ++mf)
    #pragma unroll
    for (int nf = 0; nf < 4; ++nf)
      #pragma unroll
      for (int e = 0; e < 4; ++e) acc[mf][nf][e] = 0.f;

  const int ar = tid >> 2;             // A staging row 0..63
  const int ak = (tid & 3) * 8;        // A staging k-offset

  #pragma unroll 1
  for (int kc = 0; kc < 8; ++kc) {
    const int k0 = kc * 32;
    __syncthreads();
    {
      const float* asrc = A + (size_t)(m0 + ar) * 256 + k0 + ak;
      float4 a0 = *(const float4*)asrc;
      float4 a1 = *(const float4*)(asrc + 4);
      float v[8] = {a0.x, a0.y, a0.z, a0.w, a1.x, a1.y, a1.z, a1.w};
      short8 h8, l8;
      #pragma unroll
      for (int e = 0; e < 8; ++e) {
        short h = f2bf(v[e]);
        h8[e] = h;
        l8[e] = f2bf(v[e] - bf2f(h));
      }
      *(short8*)(&Ahi[ar][ak]) = h8;
      *(short8*)(&Alo[ar][ak]) = l8;
    }
    #pragma unroll
    for (int l = 0; l < 4; ++l) {
      const int rem = tid + 256 * (l & 1);
      const int row = rem >> 2;
      const int koff = (rem & 3) * 8;
      const int n = (row < 64) ? (np0 + row) : (256 + np0 + row - 64);
      const short* src = ((l < 2) ? Bthi : Btlo) + (size_t)n * 256 + k0 + koff;
      short8 vv = *(const short8*)src;
      if (l < 2) *(short8*)(&Bhi[row][koff]) = vv;
      else       *(short8*)(&Blo[row][koff]) = vv;
    }
    __syncthreads();

    short8 ah[2], al[2], bh[4], bl[4];
    #pragma unroll
    for (int mf = 0; mf < 2; ++mf) {
      ah[mf] = *(const short8*)(&Ahi[mh * 32 + mf * 16 + l15][quad * 8]);
      al[mf] = *(const short8*)(&Alo[mh * 32 + mf * 16 + l15][quad * 8]);
    }
    #pragma unroll
    for (int nf = 0; nf < 4; ++nf) {
      bh[nf] = *(const short8*)(&Bhi[qh * 64 + nf * 16 + l15][quad * 8]);
      bl[nf] = *(const short8*)(&Blo[qh * 64 + nf * 16 + l15][quad * 8]);
    }
    #pragma unroll
    for (int mf = 0; mf < 2; ++mf)
      #pragma unroll
      for (int nf = 0; nf < 4; ++nf) {
        acc[mf][nf] = __builtin_amdgcn_mfma_f32_16x16x32_bf16(
            ah[mf], bh[nf], acc[mf][nf], 0, 0, 0);
        acc[mf][nf] = __builtin_amdgcn_mfma_f32_16x16x32_bf16(
            ah[mf], bl[nf], acc[mf][nf], 0, 0, 0);
        acc[mf][nf] = __builtin_amdgcn_mfma_f32_16x16x32_bf16(
            al[mf], bh[nf], acc[mf][nf], 0, 0, 0);
      }
  }

  if (qh == 1) {
    #pragma unroll
    for (int mf = 0; mf < 2; ++mf)
      #pragma unroll
      for (int nf = 0; nf < 4; ++nf)
        #pragma unroll
        for (int e = 0; e < 4; ++e) {
          int row = mh * 32 + mf * 16 + quad * 4 + e;
          int col = nf * 16 + l15;
          float q = acc[mf][nf][e] + sx[row][0] * swz[3][col] +
                    sx[row][1] * swz[4][col] + sx[row][2] * swz[5][col];
          Qs[row][col] = q;
          Q[(size_t)(m0 + row) * DTOK + np0 + col] = q;
        }
  }
  __syncthreads();
  if (qh == 0) {
    #pragma unroll
    for (int mf = 0; mf < 2; ++mf)
      #pragma unroll
      for (int nf = 0; nf < 4; ++nf)
        #pragma unroll
        for (int e = 0; e < 4; ++e) {
          int row = mh * 32 + mf * 16 + quad * 4 + e;
          int col = nf * 16 + l15;
          float p = acc[mf][nf][e] + sx[row][0] * swz[0][col] +
                    sx[row][1] * swz[1][col] + sx[row][2] * swz[2][col];
          R[(size_t)(m0 + row) * DTOK + np0 + col] =
              (p + sb1[col]) - Qs[row][col];
        }
  }
}

// ---------------------------------------------------------------------------
// EdgeConv via MFMA v5: W2 register cache ELIMINATED. B-fragments are loaded
// from the pre-converted bf16 Bt2 (128 KB, L2-resident) inside the kt loop
// (4 x 16B dwordx4 per kt, hidden under 8 MFMAs). Frees ~128 VGPRs so the
// build phase can keep all 16 gathers in flight (R10's prefetch couldn't --
// pressure from bfr throttled MLP). mp loop unroll(1) + per-mp kt rotation
// prevents the compiler re-hoisting the B loads into registers. B values are
// bit-identical (same f2bf); kt order only perturbs fp32 accum rounding.
// ---------------------------------------------------------------------------
#define EP 8          // points per group

__global__ __launch_bounds__(256, 2) void edge_mfma_kernel(
    const float* __restrict__ R, const float* __restrict__ Q,
    const int* __restrict__ nbr, const short* __restrict__ Bt2,
    const float* __restrict__ b2, float* __restrict__ out,
    int num_groups, int groups_per_block) {
  __shared__ short Hs[EP * KNN * DTOK];   // 128 rows x 256, 64 KB
  const int lane = threadIdx.x & 63;
  const int wave = threadIdx.x >> 6;
  const int l15 = lane & 15;
  const int quad = lane >> 4;

  const int wc8 = lane >> 1;
  const int wsub = (lane & 1) * 4;

  for (int gi = 0; gi < groups_per_block; ++gi) {
    const int g = blockIdx.x + gi * gridDim.x;
    if (g >= num_groups) break;
    const int i0 = g * EP;

    // ---- build H: prefetched nbr via lane reg + shfl, pipelined gathers ----
    {
      const int ia = i0 + wave * 2;
      const int jr0 = nbr[ia * KNN + l15];
      const int jr1 = nbr[(ia + 1) * KNN + l15];
      const float4 ri0 = ((const float4*)(R + (size_t)ia * DTOK))[lane];
      const float4 ri1 = ((const float4*)(R + (size_t)(ia + 1) * DTOK))[lane];
      #pragma unroll
      for (int pp = 0; pp < 2; ++pp) {
        const float4 ri = pp ? ri1 : ri0;
        const int jr = pp ? jr1 : jr0;
        #pragma unroll
        for (int k = 0; k < KNN; ++k) {
          const int j = __shfl(jr, k, 16);
          const float4 qj = ((const float4*)(Q + (size_t)j * DTOK))[lane];
          const int r = wave * 32 + pp * 16 + k;
          uint2 pk;
          pk.x = ((unsigned)(unsigned short)f2bf(fmaxf(ri.x + qj.x, 0.f))) |
                 (((unsigned)(unsigned short)f2bf(fmaxf(ri.y + qj.y, 0.f))) << 16);
          pk.y = ((unsigned)(unsigned short)f2bf(fmaxf(ri.z + qj.z, 0.f))) |
                 (((unsigned)(unsigned short)f2bf(fmaxf(ri.w + qj.w, 0.f))) << 16);
          *(uint2*)(&Hs[r * DTOK + ((wc8 ^ (r & 7)) << 3) + wsub]) = pk;
        }
      }
    }
    __syncthreads();

    #pragma unroll 1
    for (int mp = 0; mp < 4; ++mp) {
      float4v acc[2][4];
      #pragma unroll
      for (int mi = 0; mi < 2; ++mi)
        #pragma unroll
        for (int nt_i = 0; nt_i < 4; ++nt_i)
          #pragma unroll
          for (int e = 0; e < 4; ++e) acc[mi][nt_i][e] = 0.f;

      #pragma unroll
      for (int kk = 0; kk < 8; ++kk) {
        const int kt = (kk + 2 * mp) & 7;      // rotate: defeats LICM/CSE
        short8 bf[4];
        #pragma unroll
        for (int nt_i = 0; nt_i < 4; ++nt_i) {
          const int n = (wave * 4 + nt_i) * 16 + l15;
          bf[nt_i] = *(const short8*)(Bt2 + (size_t)n * 256 + kt * 32 +
                                      quad * 8);
        }
        const int pc = ((kt * 4 + quad) ^ (l15 & 7)) << 3;
        const short8 a0 = *(const short8*)(
            &Hs[((mp * 2 + 0) * 16 + l15) * DTOK + pc]);
        const short8 a1 = *(const short8*)(
            &Hs[((mp * 2 + 1) * 16 + l15) * DTOK + pc]);
        #pragma unroll
        for (int nt_i = 0; nt_i < 4; ++nt_i) {
          acc[0][nt_i] = __builtin_amdgcn_mfma_f32_16x16x32_bf16(
              a0, bf[nt_i], acc[0][nt_i], 0, 0, 0);
          acc[1][nt_i] = __builtin_amdgcn_mfma_f32_16x16x32_bf16(
              a1, bf[nt_i], acc[1][nt_i], 0, 0, 0);
        }
      }

      #pragma unroll
      for (int mi = 0; mi < 2; ++mi) {
        #pragma unroll
        for (int nt_i = 0; nt_i < 4; ++nt_i) {
          float rm = fmaxf(fmaxf(acc[mi][nt_i][0], acc[mi][nt_i][1]),
                           fmaxf(acc[mi][nt_i][2], acc[mi][nt_i][3]));
          rm = fmaxf(rm, __shfl_xor(rm, 16, 64));
          rm = fmaxf(rm, __shfl_xor(rm, 32, 64));
          if (lane < 16) {
            const int i = i0 + mp * 2 + mi;
            const int n = (wave * 4 + nt_i) * 16 + lane;
            out[(size_t)i * DTOK + n] = rm + b2[n];
          }
        }
      }
    }
    __syncthreads();
  }
}

// ---------------------------------------------------------------------------
extern "C" void kernel_launch(void* const* d_in, const int* in_sizes, int n_in,
                              void* d_out, int out_size, void* d_ws,
                              size_t ws_size, hipStream_t stream) {
  const float* xyz = (const float*)d_in[0];
  const float* feat = (const float*)d_in[1];
  const float* W1a = (const float*)d_in[2];
  const float* b1a = (const float*)d_in[3];
  const float* W2a = (const float*)d_in[4];
  const float* b2a = (const float*)d_in[5];
  const float* W1b = (const float*)d_in[6];
  const float* b1b = (const float*)d_in[7];
  const float* W2b = (const float*)d_in[8];
  const float* b2b = (const float*)d_in[9];
  float* out = (float*)d_out;

  // ws layout (~25.1 MB): nbr 0.5 | 16MB (knn: part / gemm: R at +8MB)
  //   | Q 8MB | Bt hi/lo 0.5MB | Bt2 128KB.  Layer-a staging in d_out.
  char* w = (char*)d_ws;
  const size_t SZ_NBR = (size_t)N_PTS * KNN * sizeof(int);        // 512 KB
  const size_t MB = 1024 * 1024;
  int* nbr = (int*)w;
  char* w1 = w + SZ_NBR;
  uint2* part = (uint2*)w1;                    // knn phase (16 MB)
  float* R = (float*)(w1 + 8 * MB);            // 8 MB (post-knn)
  float* Q = (float*)(w + SZ_NBR + 16 * MB);   // 8 MB
  short* Bthi = (short*)(w + SZ_NBR + 24 * MB);// 256 KB
  short* Btlo = Bthi + 512 * 256;              // 256 KB
  short* Bt2 = Btlo + 512 * 256;               // 128 KB
  float* bufC = out;                           // layer-a output staging

  knn_partial_kernel<<<dim3(N_PTS / 256, NCHUNK), 256, 0, stream>>>(xyz, part);
  knn_merge_kernel<<<N_PTS / 16, 256, 0, stream>>>(part, nbr);

  const int num_groups = N_PTS / EP;           // 1024
  const int nblocks = 512;

  // layer a
  convert_w_kernel<<<512, 256, 0, stream>>>(W1a, Bthi, Btlo);
  convert_w2_kernel<<<256, 256, 0, stream>>>(W2a, Bt2);
  pq_gemm_fused_kernel<<<dim3(N_PTS / 64, 4), 256, 0, stream>>>(
      feat, Bthi, Btlo, xyz, W1a, b1a, R, Q);
  edge_mfma_kernel<<<nblocks, 256, 0, stream>>>(R, Q, nbr, Bt2, b2a, bufC,
                                                num_groups, 2);

  // layer b
  convert_w_kernel<<<512, 256, 0, stream>>>(W1b, Bthi, Btlo);
  convert_w2_kernel<<<256, 256, 0, stream>>>(W2b, Bt2);
  pq_gemm_fused_kernel<<<dim3(N_PTS / 64, 4), 256, 0, stream>>>(
      bufC, Bthi, Btlo, xyz, W1b, b1b, R, Q);
  edge_mfma_kernel<<<nblocks, 256, 0, stream>>>(R, Q, nbr, Bt2, b2b, out,
                                                num_groups, 2);
}

// Round 12
// 265.310 us; speedup vs baseline: 1.4375x; 1.4375x over previous
//
#include <hip/hip_runtime.h>
#include <cfloat>

#define N_PTS 8192
#define DTOK 256
#define KNN 16

typedef __attribute__((ext_vector_type(8))) short short8;
typedef __attribute__((ext_vector_type(4))) float float4v;

__device__ inline short f2bf(float f) {   // RTNE fp32 -> bf16
  unsigned u = __float_as_uint(f);
  u += 0x7fffu + ((u >> 16) & 1u);
  return (short)(u >> 16);
}
__device__ inline float bf2f(short h) {
  return __uint_as_float(((unsigned)(unsigned short)h) << 16);
}

// ---------------------------------------------------------------------------
// Pack xyz -> (x,y,z,sq) with the exact rounding the old knn used, so all
// distances (and thus KNN indices) are bit-identical.
// ---------------------------------------------------------------------------
__global__ __launch_bounds__(256) void knn_prep_kernel(
    const float* __restrict__ xyz, float4* __restrict__ xyz4) {
  const int i = blockIdx.x * 256 + threadIdx.x;
  float x = xyz[3 * i], y = xyz[3 * i + 1], z = xyz[3 * i + 2];
  float sq = __fadd_rn(__fadd_rn(__fmul_rn(x, x), __fmul_rn(y, y)),
                       __fmul_rn(z, z));
  xyz4[i] = make_float4(x, y, z, sq);
}

// ---------------------------------------------------------------------------
// KNN v4: wave-per-point streaming top-16, replaces partial+merge entirely.
// Lanes 0..15 hold the point's sorted top-16 (ascending d) ACROSS LANES.
// Per iter: 64 lanes compute 64 candidate distances; __ballot(d < s15)
// (strict <, matches reference tie rule) selects survivors; each survivor
// is inserted via ballot(sd<=dc)-popcount position (stable: earlier j stays
// in front) + shfl_up shift. ~116 inserts/point expected (harmonic).
// No LDS, no FIFO/drain, no merge kernel, no 16MB part traffic; 8192 waves
// -> 8 waves/SIMD (vs 2 before). xyz4 (128 KB) is L2-resident.
// ---------------------------------------------------------------------------
__global__ __launch_bounds__(256) void knn_select_kernel(
    const float4* __restrict__ xyz4, int* __restrict__ nbr) {
  const int lane = threadIdx.x & 63;
  const int i = blockIdx.x * 4 + (threadIdx.x >> 6);

  const float4 pi = xyz4[i];
  const float xi = pi.x, yi = pi.y, zi = pi.z, sqi = pi.w;

  float sd = FLT_MAX;      // slot distance (lanes 0..15 meaningful)
  int sj = 0;              // slot index
  float s15 = FLT_MAX;     // current 16th-best (uniform)

  for (int base = 0; base < N_PTS; base += 64) {
    const int j = base + lane;
    const float4 p = xyz4[j];
    const float dot = fmaf(zi, p.z, fmaf(yi, p.y, __fmul_rn(xi, p.x)));
    float d = __fadd_rn(__fsub_rn(sqi, __fmul_rn(2.0f, dot)), p.w);
    if (j == i) d = __fadd_rn(d, 1e10f);

    unsigned long long m = __ballot(d < s15);
    while (m) {                          // m is wave-uniform
      const int src = __ffsll(m) - 1;    // ascending lane == ascending j
      m &= m - 1;
      const float dc = __shfl(d, src);
      if (dc < s15) {                    // recheck vs tightened bound
        const int jc = base + src;
        const unsigned long long bm = __ballot(sd <= dc) & 0xFFFFull;
        const int pos = (int)__popcll(bm);      // stable position
        const float pu = __shfl_up(sd, 1);
        const int ju = __shfl_up(sj, 1);
        if (lane < 16) {
          if (lane > pos)        { sd = pu; sj = ju; }
          else if (lane == pos)  { sd = dc; sj = jc; }
        }
        s15 = __shfl(sd, 15);
      }
    }
  }
  if (lane < 16) nbr[i * KNN + lane] = sj;
}

// ---------------------------------------------------------------------------
// W1 -> Bt (transposed, n-major) bf16 hi/lo (frozen).
// ---------------------------------------------------------------------------
__global__ __launch_bounds__(256) void convert_w_kernel(
    const float* __restrict__ W1, short* __restrict__ bhi,
    short* __restrict__ blo) {
  const int n = blockIdx.x;      // 0..511
  const int k = threadIdx.x;     // 0..255
  const float v = (n < 256) ? W1[k * DTOK + n]
                            : W1[(259 + k) * DTOK + (n - 256)];
  short h = f2bf(v);
  bhi[n * 256 + k] = h;
  blo[n * 256 + k] = f2bf(v - bf2f(h));
}

// ---------------------------------------------------------------------------
// pq GEMM v2 (frozen from R9).
// ---------------------------------------------------------------------------
__global__ __launch_bounds__(256, 2) void pq_gemm_fused_kernel(
    const float* __restrict__ A, const short* __restrict__ Bthi,
    const short* __restrict__ Btlo, const float* __restrict__ xyz,
    const float* __restrict__ W1, const float* __restrict__ b1,
    float* __restrict__ R, float* __restrict__ Q) {
  __shared__ short Ahi[64][32], Alo[64][32];    // 4K + 4K
  __shared__ short Bhi[128][32], Blo[128][32];  // 8K + 8K
  __shared__ float Qs[64][65];                  // 16.6K
  __shared__ float sx[64][3];
  __shared__ float swz[6][64];
  __shared__ float sb1[64];

  const int tid = threadIdx.x;
  const int lane = tid & 63;
  const int wave = tid >> 6;
  const int l15 = lane & 15;
  const int quad = lane >> 4;
  const int mh = wave & 1;
  const int qh = wave >> 1;
  const int m0 = blockIdx.x * 64;
  const int np0 = blockIdx.y * 64;

  if (tid < 64) {
    sx[tid][0] = xyz[(m0 + tid) * 3];
    sx[tid][1] = xyz[(m0 + tid) * 3 + 1];
    sx[tid][2] = xyz[(m0 + tid) * 3 + 2];
  } else if (tid < 128) {
    int n = tid - 64;
    sb1[n] = b1[np0 + n];
    #pragma unroll
    for (int r = 0; r < 3; ++r) {
      swz[r][n] = W1[(256 + r) * DTOK + np0 + n];
      swz[3 + r][n] = W1[(515 + r) * DTOK + np0 + n];
    }
  }

  float4v acc[2][4];
  #pragma unroll
  for (int mf = 0; mf < 2; ++mf)
    #pragma unroll
    for (int nf = 0; nf < 4; ++nf)
      #pragma unroll
      for (int e = 0; e < 4; ++e) acc[mf][nf][e] = 0.f;

  const int ar = tid >> 2;             // A staging row 0..63
  const int ak = (tid & 3) * 8;        // A staging k-offset

  #pragma unroll 1
  for (int kc = 0; kc < 8; ++kc) {
    const int k0 = kc * 32;
    __syncthreads();
    {
      const float* asrc = A + (size_t)(m0 + ar) * 256 + k0 + ak;
      float4 a0 = *(const float4*)asrc;
      float4 a1 = *(const float4*)(asrc + 4);
      float v[8] = {a0.x, a0.y, a0.z, a0.w, a1.x, a1.y, a1.z, a1.w};
      short8 h8, l8;
      #pragma unroll
      for (int e = 0; e < 8; ++e) {
        short h = f2bf(v[e]);
        h8[e] = h;
        l8[e] = f2bf(v[e] - bf2f(h));
      }
      *(short8*)(&Ahi[ar][ak]) = h8;
      *(short8*)(&Alo[ar][ak]) = l8;
    }
    #pragma unroll
    for (int l = 0; l < 4; ++l) {
      const int rem = tid + 256 * (l & 1);
      const int row = rem >> 2;
      const int koff = (rem & 3) * 8;
      const int n = (row < 64) ? (np0 + row) : (256 + np0 + row - 64);
      const short* src = ((l < 2) ? Bthi : Btlo) + (size_t)n * 256 + k0 + koff;
      short8 vv = *(const short8*)src;
      if (l < 2) *(short8*)(&Bhi[row][koff]) = vv;
      else       *(short8*)(&Blo[row][koff]) = vv;
    }
    __syncthreads();

    short8 ah[2], al[2], bh[4], bl[4];
    #pragma unroll
    for (int mf = 0; mf < 2; ++mf) {
      ah[mf] = *(const short8*)(&Ahi[mh * 32 + mf * 16 + l15][quad * 8]);
      al[mf] = *(const short8*)(&Alo[mh * 32 + mf * 16 + l15][quad * 8]);
    }
    #pragma unroll
    for (int nf = 0; nf < 4; ++nf) {
      bh[nf] = *(const short8*)(&Bhi[qh * 64 + nf * 16 + l15][quad * 8]);
      bl[nf] = *(const short8*)(&Blo[qh * 64 + nf * 16 + l15][quad * 8]);
    }
    #pragma unroll
    for (int mf = 0; mf < 2; ++mf)
      #pragma unroll
      for (int nf = 0; nf < 4; ++nf) {
        acc[mf][nf] = __builtin_amdgcn_mfma_f32_16x16x32_bf16(
            ah[mf], bh[nf], acc[mf][nf], 0, 0, 0);
        acc[mf][nf] = __builtin_amdgcn_mfma_f32_16x16x32_bf16(
            ah[mf], bl[nf], acc[mf][nf], 0, 0, 0);
        acc[mf][nf] = __builtin_amdgcn_mfma_f32_16x16x32_bf16(
            al[mf], bh[nf], acc[mf][nf], 0, 0, 0);
      }
  }

  if (qh == 1) {
    #pragma unroll
    for (int mf = 0; mf < 2; ++mf)
      #pragma unroll
      for (int nf = 0; nf < 4; ++nf)
        #pragma unroll
        for (int e = 0; e < 4; ++e) {
          int row = mh * 32 + mf * 16 + quad * 4 + e;
          int col = nf * 16 + l15;
          float q = acc[mf][nf][e] + sx[row][0] * swz[3][col] +
                    sx[row][1] * swz[4][col] + sx[row][2] * swz[5][col];
          Qs[row][col] = q;
          Q[(size_t)(m0 + row) * DTOK + np0 + col] = q;
        }
  }
  __syncthreads();
  if (qh == 0) {
    #pragma unroll
    for (int mf = 0; mf < 2; ++mf)
      #pragma unroll
      for (int nf = 0; nf < 4; ++nf)
        #pragma unroll
        for (int e = 0; e < 4; ++e) {
          int row = mh * 32 + mf * 16 + quad * 4 + e;
          int col = nf * 16 + l15;
          float p = acc[mf][nf][e] + sx[row][0] * swz[0][col] +
                    sx[row][1] * swz[1][col] + sx[row][2] * swz[2][col];
          R[(size_t)(m0 + row) * DTOK + np0 + col] =
              (p + sb1[col]) - Qs[row][col];
        }
  }
}

// ---------------------------------------------------------------------------
// EdgeConv via MFMA (EXACT R10 version -- R11's global-B variant regressed
// 68 -> ~110 us/launch; W2 register fragments restored).
// ---------------------------------------------------------------------------
#define EP 8          // points per group

__global__ __launch_bounds__(256, 2) void edge_mfma_kernel(
    const float* __restrict__ R, const float* __restrict__ Q,
    const int* __restrict__ nbr, const float* __restrict__ W2,
    const float* __restrict__ b2, float* __restrict__ out,
    int num_groups, int groups_per_block) {
  __shared__ short Hs[EP * KNN * DTOK];   // 128 rows x 256, 64 KB
  const int lane = threadIdx.x & 63;
  const int wave = threadIdx.x >> 6;
  const int l15 = lane & 15;
  const int quad = lane >> 4;

  short8 bfr[4][8];
  #pragma unroll
  for (int nt_i = 0; nt_i < 4; ++nt_i) {
    const int n = (wave * 4 + nt_i) * 16 + l15;
    #pragma unroll
    for (int kt = 0; kt < 8; ++kt) {
      short8 f;
      #pragma unroll
      for (int jj = 0; jj < 8; ++jj) {
        int k = kt * 32 + quad * 8 + jj;
        f[jj] = f2bf(W2[k * DTOK + n]);
      }
      bfr[nt_i][kt] = f;
    }
  }

  const int wc8 = lane >> 1;
  const int wsub = (lane & 1) * 4;

  for (int gi = 0; gi < groups_per_block; ++gi) {
    const int g = blockIdx.x + gi * gridDim.x;
    if (g >= num_groups) break;
    const int i0 = g * EP;

    // ---- build H: prefetched nbr via lane reg + shfl, pipelined gathers ----
    {
      const int ia = i0 + wave * 2;
      const int jr0 = nbr[ia * KNN + l15];
      const int jr1 = nbr[(ia + 1) * KNN + l15];
      const float4 ri0 = ((const float4*)(R + (size_t)ia * DTOK))[lane];
      const float4 ri1 = ((const float4*)(R + (size_t)(ia + 1) * DTOK))[lane];
      #pragma unroll
      for (int pp = 0; pp < 2; ++pp) {
        const float4 ri = pp ? ri1 : ri0;
        const int jr = pp ? jr1 : jr0;
        #pragma unroll
        for (int k = 0; k < KNN; ++k) {
          const int j = __shfl(jr, k, 16);
          const float4 qj = ((const float4*)(Q + (size_t)j * DTOK))[lane];
          const int r = wave * 32 + pp * 16 + k;
          uint2 pk;
          pk.x = ((unsigned)(unsigned short)f2bf(fmaxf(ri.x + qj.x, 0.f))) |
                 (((unsigned)(unsigned short)f2bf(fmaxf(ri.y + qj.y, 0.f))) << 16);
          pk.y = ((unsigned)(unsigned short)f2bf(fmaxf(ri.z + qj.z, 0.f))) |
                 (((unsigned)(unsigned short)f2bf(fmaxf(ri.w + qj.w, 0.f))) << 16);
          *(uint2*)(&Hs[r * DTOK + ((wc8 ^ (r & 7)) << 3) + wsub]) = pk;
        }
      }
    }
    __syncthreads();

    #pragma unroll
    for (int mp = 0; mp < 4; ++mp) {
      float4v acc[2][4];
      #pragma unroll
      for (int mi = 0; mi < 2; ++mi)
        #pragma unroll
        for (int nt_i = 0; nt_i < 4; ++nt_i)
          #pragma unroll
          for (int e = 0; e < 4; ++e) acc[mi][nt_i][e] = 0.f;

      #pragma unroll
      for (int kt = 0; kt < 8; ++kt) {
        const int pc = ((kt * 4 + quad) ^ (l15 & 7)) << 3;
        const short8 a0 = *(const short8*)(
            &Hs[((mp * 2 + 0) * 16 + l15) * DTOK + pc]);
        const short8 a1 = *(const short8*)(
            &Hs[((mp * 2 + 1) * 16 + l15) * DTOK + pc]);
        #pragma unroll
        for (int nt_i = 0; nt_i < 4; ++nt_i) {
          acc[0][nt_i] = __builtin_amdgcn_mfma_f32_16x16x32_bf16(
              a0, bfr[nt_i][kt], acc[0][nt_i], 0, 0, 0);
          acc[1][nt_i] = __builtin_amdgcn_mfma_f32_16x16x32_bf16(
              a1, bfr[nt_i][kt], acc[1][nt_i], 0, 0, 0);
        }
      }

      #pragma unroll
      for (int mi = 0; mi < 2; ++mi) {
        #pragma unroll
        for (int nt_i = 0; nt_i < 4; ++nt_i) {
          float rm = fmaxf(fmaxf(acc[mi][nt_i][0], acc[mi][nt_i][1]),
                           fmaxf(acc[mi][nt_i][2], acc[mi][nt_i][3]));
          rm = fmaxf(rm, __shfl_xor(rm, 16, 64));
          rm = fmaxf(rm, __shfl_xor(rm, 32, 64));
          if (lane < 16) {
            const int i = i0 + mp * 2 + mi;
            const int n = (wave * 4 + nt_i) * 16 + lane;
            out[(size_t)i * DTOK + n] = rm + b2[n];
          }
        }
      }
    }
    __syncthreads();
  }
}

// ---------------------------------------------------------------------------
extern "C" void kernel_launch(void* const* d_in, const int* in_sizes, int n_in,
                              void* d_out, int out_size, void* d_ws,
                              size_t ws_size, hipStream_t stream) {
  const float* xyz = (const float*)d_in[0];
  const float* feat = (const float*)d_in[1];
  const float* W1a = (const float*)d_in[2];
  const float* b1a = (const float*)d_in[3];
  const float* W2a = (const float*)d_in[4];
  const float* b2a = (const float*)d_in[5];
  const float* W1b = (const float*)d_in[6];
  const float* b1b = (const float*)d_in[7];
  const float* W2b = (const float*)d_in[8];
  const float* b2b = (const float*)d_in[9];
  float* out = (float*)d_out;

  // ws layout (~25 MB): nbr 0.5 | xyz4 128KB (then R at +8MB) | Q | Bt hi/lo
  char* w = (char*)d_ws;
  const size_t SZ_NBR = (size_t)N_PTS * KNN * sizeof(int);        // 512 KB
  const size_t MB = 1024 * 1024;
  int* nbr = (int*)w;
  char* w1 = w + SZ_NBR;
  float4* xyz4 = (float4*)w1;                  // 128 KB
  float* R = (float*)(w1 + 8 * MB);            // 8 MB
  float* Q = (float*)(w + SZ_NBR + 16 * MB);   // 8 MB
  short* Bthi = (short*)(w + SZ_NBR + 24 * MB);// 256 KB
  short* Btlo = Bthi + 512 * 256;              // 256 KB
  float* bufC = out;                           // layer-a output staging

  knn_prep_kernel<<<N_PTS / 256, 256, 0, stream>>>(xyz, xyz4);
  knn_select_kernel<<<N_PTS / 4, 256, 0, stream>>>(xyz4, nbr);

  const int num_groups = N_PTS / EP;           // 1024
  const int nblocks = 512;

  // layer a
  convert_w_kernel<<<512, 256, 0, stream>>>(W1a, Bthi, Btlo);
  pq_gemm_fused_kernel<<<dim3(N_PTS / 64, 4), 256, 0, stream>>>(
      feat, Bthi, Btlo, xyz, W1a, b1a, R, Q);
  edge_mfma_kernel<<<nblocks, 256, 0, stream>>>(R, Q, nbr, W2a, b2a, bufC,
                                                num_groups, 2);

  // layer b
  convert_w_kernel<<<512, 256, 0, stream>>>(W1b, Bthi, Btlo);
  pq_gemm_fused_kernel<<<dim3(N_PTS / 64, 4), 256, 0, stream>>>(
      bufC, Bthi, Btlo, xyz, W1b, b1b, R, Q);
  edge_mfma_kernel<<<nblocks, 256, 0, stream>>>(R, Q, nbr, W2b, b2b, out,
                                                num_groups, 2);
}